// Round 1
// baseline (241.362 us; speedup 1.0000x reference)
//
#include <hip/hip_runtime.h>
#include <math.h>

// LinearAttend: B=4, N=8, D=64, S=8192, fp32 in/out.
// out[j,s] = (QSCALE/W_s) * sum_i (ctx[i,j]/Z_i) * exp(q[i,s])
//   ctx[i,j] = sum_s exp(k[i,s]) * v[j,s],  Z_i = sum_s exp(k[i,s])
// 3-kernel pipeline, zero atomics:
//   1) ctx_partial: 32-way split-K fp16-MFMA partials, BARRIER-FREE:
//      A/B fragments loaded directly from global (seq is the contiguous
//      axis == MFMA k-axis), exp+cvt in registers, 2-deep reg pipeline.
//      No LDS -> no s_waitcnt vmcnt(0) barrier drains (the old 54us stall).
//   2) reduce: 512 blocks (was 128), sum 32 chunk-partials, fold 1/Z,
//      emit fp16 czT[j][i]. No LDS/barriers.
//   3) out: 32x32x16 fp16 MFMA -> full-cacheline stores (unchanged).

typedef _Float16 half8 __attribute__((ext_vector_type(8)));
typedef float floatx4 __attribute__((ext_vector_type(4)));
typedef float floatx16 __attribute__((ext_vector_type(16)));

constexpr int BHEADS = 32;
constexpr int DH     = 64;
constexpr int SEQ    = 8192;
constexpr int NCHUNK = 32;          // split-K chunks of 256 s
constexpr float QSCALE = 0.125f;    // 64^-0.5

// ---------------------------------------------------------------------------
// Kernel 1: partial[head][chunk][i][j] = sum_{s in chunk} e[i,s]*v[j,s]
//           Zp[head][chunk][i]         = sum_{s in chunk} e[i,s]
// grid (32 chunks x 32 heads) = 1024 blocks. 4 independent waves/block,
// wave w owns i-rows [16w,16w+16). 8 K-steps of 32 s, fully pipelined,
// NO LDS, NO __syncthreads.
// Fragment map (16x16x32 f16): lane = ln + 16*q8 holds
//   A[m=ln][k=q8*8 .. q8*8+8) = exp(K[16w+ln][s0+kk*32+q8*8 ..])  (contiguous!)
//   B[n=ln][k=...]            =      V[16jt+ln][s0+kk*32+q8*8 ..]
//   C/D: col=ln, row=q8*4+reg   [verified layout, unchanged from prev kernel]
// ---------------------------------------------------------------------------
__global__ __launch_bounds__(256)
void ctx_partial_kernel(const float* __restrict__ K, const float* __restrict__ V,
                        float* __restrict__ partial, float* __restrict__ Zp)
{
    const int head  = blockIdx.y;
    const int chunk = blockIdx.x;
    const int t     = threadIdx.x;
    const int lane  = t & 63;
    const int w     = t >> 6;        // i-group
    const int ln    = lane & 15;
    const int q8    = lane >> 4;

    const int s0 = chunk * 256;
    const float* ka = K + (size_t)head * DH * SEQ
                        + (size_t)(16 * w + ln) * SEQ + s0 + q8 * 8;
    const float* va = V + (size_t)head * DH * SEQ
                        + (size_t)ln * SEQ + s0 + q8 * 8;

    floatx4 acc[4];
    #pragma unroll
    for (int jt = 0; jt < 4; ++jt) acc[jt] = (floatx4){0.f, 0.f, 0.f, 0.f};
    float zacc = 0.f;

    // 2-deep register double-buffer: 10 float4 in flight per stage
    float4 cak[2][2];
    float4 cbv[2][4][2];

    cak[0][0] = *(const float4*)(ka);
    cak[0][1] = *(const float4*)(ka + 4);
    #pragma unroll
    for (int jt = 0; jt < 4; ++jt) {
        cbv[0][jt][0] = *(const float4*)(va + (size_t)jt * 16 * SEQ);
        cbv[0][jt][1] = *(const float4*)(va + (size_t)jt * 16 * SEQ + 4);
    }

    #pragma unroll
    for (int kk = 0; kk < 8; ++kk) {
        const int cur = kk & 1;          // static after unroll (rule #20 safe)
        const int nxt = cur ^ 1;
        if (kk < 7) {                    // issue next stage before computing
            const int off = (kk + 1) * 32;
            cak[nxt][0] = *(const float4*)(ka + off);
            cak[nxt][1] = *(const float4*)(ka + off + 4);
            #pragma unroll
            for (int jt = 0; jt < 4; ++jt) {
                cbv[nxt][jt][0] = *(const float4*)(va + (size_t)jt * 16 * SEQ + off);
                cbv[nxt][jt][1] = *(const float4*)(va + (size_t)jt * 16 * SEQ + off + 4);
            }
        }
        float e[8];
        e[0] = __expf(cak[cur][0].x); e[1] = __expf(cak[cur][0].y);
        e[2] = __expf(cak[cur][0].z); e[3] = __expf(cak[cur][0].w);
        e[4] = __expf(cak[cur][1].x); e[5] = __expf(cak[cur][1].y);
        e[6] = __expf(cak[cur][1].z); e[7] = __expf(cak[cur][1].w);
        zacc += e[0]+e[1]+e[2]+e[3]+e[4]+e[5]+e[6]+e[7];
        half8 ah;
        #pragma unroll
        for (int x = 0; x < 8; ++x) ah[x] = (_Float16)e[x];
        #pragma unroll
        for (int jt = 0; jt < 4; ++jt) {
            half8 bh;
            bh[0] = (_Float16)cbv[cur][jt][0].x; bh[1] = (_Float16)cbv[cur][jt][0].y;
            bh[2] = (_Float16)cbv[cur][jt][0].z; bh[3] = (_Float16)cbv[cur][jt][0].w;
            bh[4] = (_Float16)cbv[cur][jt][1].x; bh[5] = (_Float16)cbv[cur][jt][1].y;
            bh[6] = (_Float16)cbv[cur][jt][1].z; bh[7] = (_Float16)cbv[cur][jt][1].w;
            acc[jt] = __builtin_amdgcn_mfma_f32_16x16x32_f16(ah, bh, acc[jt], 0, 0, 0);
        }
    }

    float* ph = partial + (size_t)(head * NCHUNK + chunk) * DH * DH;
    #pragma unroll
    for (int jt = 0; jt < 4; ++jt) {
        #pragma unroll
        for (int rr = 0; rr < 4; ++rr) {
            const int i = 16 * w + q8 * 4 + rr;
            const int j = 16 * jt + ln;
            ph[i * DH + j] = acc[jt][rr];
        }
    }

    // Z[i] = sum over the 4 q8 col-groups (lanes ln, ln+16, ln+32, ln+48)
    zacc += __shfl_xor(zacc, 16);
    zacc += __shfl_xor(zacc, 32);
    if (lane < 16)
        Zp[(head * NCHUNK + chunk) * DH + 16 * w + ln] = zacc;
}

// ---------------------------------------------------------------------------
// Kernel 2: czT[head][j][i] = (1/Z_i) * sum_c partial[head][c][i][j]  (fp16)
// grid 512 blocks: (head, 4-row i-group) -> 2 blocks/CU (was 0.5/CU).
// Per-c loads are 1 KiB contiguous per block. Z summed redundantly per
// thread (32 L2-broadcast scalar loads) -> no LDS, no barriers.
// ---------------------------------------------------------------------------
__global__ __launch_bounds__(256)
void reduce_kernel(const float* __restrict__ partial, const float* __restrict__ Zp,
                   _Float16* __restrict__ czT)
{
    const int h  = blockIdx.x >> 4;
    const int ig = blockIdx.x & 15;       // i rows [4*ig, 4*ig+4)
    const int t  = threadIdx.x;
    const int il = t >> 6;                // 0..3
    const int j  = t & 63;
    const int i  = 4 * ig + il;

    const float* ph = partial + (size_t)h * NCHUNK * DH * DH + i * DH + j;
    float sum = 0.f;
    #pragma unroll
    for (int c = 0; c < NCHUNK; ++c)
        sum += ph[(size_t)c * DH * DH];

    float z = 0.f;
    #pragma unroll
    for (int c = 0; c < NCHUNK; ++c)
        z += Zp[(h * NCHUNK + c) * DH + i];

    czT[(size_t)h * DH * DH + j * DH + i] = (_Float16)(sum / z);
}

// ---------------------------------------------------------------------------
// Kernel 3: out[j][s] = rw[s] * sum_i czT[j][i] * eq[i][s]
// grid (64 s-blocks x 32 heads) = 2048 blocks, 2 rounds of 64 s.
// 32x32x16 MFMA: C col spans 32 s -> every store = two full 128-B lines.
//   A[m=lane&31][k=8*(lane>>5)+j], B[n=lane&31][k=8*(lane>>5)+j]
//   C/D: col=lane&31, row=(reg&3)+8*(reg>>2)+4*(lane>>5)   [m74/m101]
// (unchanged this round)
// ---------------------------------------------------------------------------
__global__ __launch_bounds__(256)
void out_kernel(const float* __restrict__ Q, const _Float16* __restrict__ czT,
                float* __restrict__ out)
{
    const int head = blockIdx.y;
    const int sb   = blockIdx.x;
    const int t    = threadIdx.x;
    const int lane = t & 63;
    const int w    = t >> 6;
    const int l31  = lane & 31;
    const int lh   = lane >> 5;
    const int jw   = 32 * (w & 1);        // wave's j-strip
    const int sw   = 32 * (w >> 1);       // wave's s-strip within round

    __shared__ __align__(16) float    qf[64 * 68];   // fp32 natural [i][s]
    __shared__ __align__(16) _Float16 eqT[64 * 64];  // [s][i] fp16, XOR-chunk swizzle
    __shared__ __align__(16) float    wred[64 * 4];  // [s][4 partials]

    const float* qh = Q + (size_t)head * DH * SEQ;
    const int r0 = t >> 4;
    const int sc = 4 * (t & 15);
    const int s0 = sb * 128;

    float4 pq[4];
    #pragma unroll
    for (int p = 0; p < 4; ++p)
        pq[p] = *(const float4*)(qh + (size_t)(r0 + 16 * p) * SEQ + s0 + sc);

    // persistent A-frags from global czT (L2-hot, 8 KiB/head)
    const _Float16* ch = czT + (size_t)head * DH * DH;
    half8 afr[4];
    #pragma unroll
    for (int st = 0; st < 4; ++st)
        afr[st] = *(const half8*)(ch + (jw + l31) * DH + st * 16 + lh * 8);

    for (int r = 0; r < 2; ++r) {
        #pragma unroll
        for (int p = 0; p < 4; ++p)
            *(float4*)(qf + (r0 + 16 * p) * 68 + sc) = pq[p];
        // issue next round's loads right after consumption
        if (r < 1) {
            #pragma unroll
            for (int p = 0; p < 4; ++p)
                pq[p] = *(const float4*)(qh + (size_t)(r0 + 16 * p) * SEQ
                                         + s0 + 64 + sc);
        }
        __syncthreads();
        // transpose + exp + column-sum partials
        {
            const int s  = t & 63;
            const int cg = t >> 6;
            float wsum = 0.f;
            #pragma unroll
            for (int h2 = 0; h2 < 2; ++h2) {
                const int cc = cg + 4 * h2;
                half8 p8;
                #pragma unroll
                for (int jj = 0; jj < 8; ++jj) {
                    const float e = __expf(qf[(8 * cc + jj) * 68 + s]);
                    wsum += e;
                    p8[jj] = (_Float16)e;
                }
                *(half8*)(eqT + s * 64 + ((cc ^ (s & 7)) * 8)) = p8;
            }
            wred[s * 4 + cg] = wsum;
        }
        __syncthreads();
        // per-lane softmax denom for this lane's s column
        const float4 wv = *(const float4*)(wred + (sw + l31) * 4);
        const float rw = QSCALE / (wv.x + wv.y + wv.z + wv.w);
        // 32x32 tile: 4 K-steps of 16
        floatx16 acc = {};
        #pragma unroll
        for (int st = 0; st < 4; ++st) {
            const int s2 = sw + l31;
            const int cc = 2 * st + lh;
            const half8 b = *(const half8*)(eqT + s2 * 64 + ((cc ^ (s2 & 7)) * 8));
            acc = __builtin_amdgcn_mfma_f32_32x32x16_f16(afr[st], b, acc, 0, 0, 0);
        }
        // full-line stores: lanes 0..31 cover 128 B at row j1, lanes 32..63 row j1+4
        float* oh = out + (size_t)head * DH * SEQ + s0 + r * 64;
        #pragma unroll
        for (int rg = 0; rg < 16; ++rg) {
            const int j = jw + (rg & 3) + 8 * (rg >> 2) + 4 * lh;
            oh[(size_t)j * SEQ + sw + l31] = acc[rg] * rw;
        }
    }
}

extern "C" void kernel_launch(void* const* d_in, const int* in_sizes, int n_in,
                              void* d_out, int out_size, void* d_ws, size_t ws_size,
                              hipStream_t stream)
{
    const float* q = (const float*)d_in[0];
    const float* k = (const float*)d_in[1];
    const float* v = (const float*)d_in[2];
    float* out = (float*)d_out;

    float*    partial = (float*)d_ws;                           // 16 MiB
    float*    Zp      = partial + BHEADS * NCHUNK * DH * DH;    // 256 KiB
    _Float16* czT     = (_Float16*)(Zp + BHEADS * NCHUNK * DH); // 256 KiB

    ctx_partial_kernel<<<dim3(NCHUNK, BHEADS), 256, 0, stream>>>(k, v, partial, Zp);
    reduce_kernel<<<BHEADS * 16, 256, 0, stream>>>(partial, Zp, czT);
    out_kernel<<<dim3(64, BHEADS), 256, 0, stream>>>(q, czT, out);
}